// Round 5
// baseline (870308.984 us; speedup 1.0000x reference)
//
#include <hip/hip_runtime.h>
#include <math.h>

typedef __bf16 bf16;
typedef __attribute__((ext_vector_type(4))) __bf16 bf16x4;
typedef __attribute__((ext_vector_type(8))) __bf16 bf16x8;
typedef __attribute__((ext_vector_type(4))) float f32x4;

#define T_STEPS 128
#define B_SZ    256
#define V_SZ    256
#define N_SZ    1024
#define NROWS   (T_STEPS * B_SZ)   // 32768
#define RSTR    68                 // step reduction stride (floats)
#define LSTR    17                 // loss reduction stride (floats)
#define NGRP    16                 // row groups (16 batch rows each)
#define NCB     16                 // col blocks per group (64 cols each)
#define SPIN_CAP (1 << 20)         // fast-poll watchdog: downgrade to agent scope

__device__ __forceinline__ float fast_tanh(float x) {
    float e = __expf(2.0f * x);
    return 1.0f - 2.0f / (e + 1.0f);   // exact at +-inf, no NaN
}

__device__ __forceinline__ bf16x8 cvt_bf16x8(float4 a, float4 b) {
    bf16x8 r;
    r[0] = (bf16)a.x; r[1] = (bf16)a.y; r[2] = (bf16)a.z; r[3] = (bf16)a.w;
    r[4] = (bf16)b.x; r[5] = (bf16)b.y; r[6] = (bf16)b.z; r[7] = (bf16)b.w;
    return r;
}

// ---------------- one-shot prep: all three fp32->bf16 transposes -------------------
__global__ __launch_bounds__(256) void k_prep(
    const float* __restrict__ weights,   // (V+N) x N  = 1280 x 1024
    const float* __restrict__ out_w,     // N x V      = 1024 x 256
    bf16* __restrict__ Wxt,              // 1024 x 256
    bf16* __restrict__ Wht,              // 1024 x 1024
    bf16* __restrict__ Wot)              // 256 x 1024
{
    __shared__ float tile[32][33];
    int id = blockIdx.x;
    const float* src; bf16* dst; int R, C, tr, tc;
    if (id < 256) {            // Wx: rows 0..255 of weights -> Wxt
        src = weights; dst = Wxt; R = V_SZ; C = N_SZ;
        tr = (id & 7) * 32; tc = (id >> 3) * 32;
    } else if (id < 1280) {    // Wh: rows 256..1279 of weights -> Wht
        id -= 256;
        src = weights + (size_t)V_SZ * N_SZ; dst = Wht; R = N_SZ; C = N_SZ;
        tr = (id & 31) * 32; tc = (id >> 5) * 32;
    } else {                   // Wo: out_w -> Wot
        id -= 1280;
        src = out_w; dst = Wot; R = N_SZ; C = V_SZ;
        tr = (id & 31) * 32; tc = (id >> 5) * 32;
    }
    int tx = threadIdx.x & 31;
    int ty = threadIdx.x >> 5;   // 0..7
#pragma unroll
    for (int i = 0; i < 32; i += 8)
        tile[ty + i][tx] = src[(size_t)(tr + ty + i) * C + tc + tx];
    __syncthreads();
#pragma unroll
    for (int i = 0; i < 32; i += 8)
        dst[(size_t)(tc + ty + i) * R + tr + tx] = (bf16)tile[tx][ty + i];
}

// ---------------- persistent recurrence + fused Xproj + fused loss GEMM ------------
// R16 = R15's XCD-clustered L2-local sync, hardened:
//   - XCC_ID read via SYMBOLIC hwreg(HW_REG_XCC_ID) (the m09-verified form).
//   - fast poll asm uses saddr form: SGPR-pair base + 32-bit VGPR offset.
//   - every fast poll has a watchdog: after SPIN_CAP spins it permanently
//     downgrades to agent-scope polling => the kernel can never hang.
//   - verification failure => proven R12 agent-scope per-producer-flag protocol.
// Fast path (all 16 blocks of a group verified on ONE XCD):
//   H stores + flag stores: workgroup-scope (plain, write-through L1 -> shared L2);
//   consumer polls with sc0 load (bypass L1, hit shared L2); A-loads plain
//   first-touch -> L2 hit. Whole producer->consumer edge stays in-XCD.
// Loss epilogue (lred reads + logit store) deferred past the flag publish with
// parity-double lred[2]; WAR closed by collective #2/#B barriers (see comments).
__global__ __launch_bounds__(512, 2) void k_rnn(
    const float* __restrict__ Xf,   // 32768 x 256 fp32 inputs (t-major)
    const bf16* __restrict__ Wxt,   // 1024 x 256  = Wx^T
    const bf16* __restrict__ Wht,   // 1024 x 1024 = Wh^T
    const bf16* __restrict__ Wot,   // 256 x 1024  = Wo^T
    const float* __restrict__ bias,
    bf16* __restrict__ XH,          // 32768 x 1024 H states
    unsigned int* __restrict__ Lgu, // bf16-pair logits, slab layout [p][c][256][8]
    int* __restrict__ flg,          // [NGRP][16] monotonic producer counters, zeroed
    int* __restrict__ xtab)         // [NGRP][16] XCC table, init -1
{
    __shared__ float red[8 * 16 * RSTR];      // 34.8 KB step K-reduce
    __shared__ float lred[2][8 * 16 * LSTR];  // 2 x 8.7 KB loss K-reduce (parity)
    const int tid  = threadIdx.x;
    const int lane = tid & 63;
    const int w    = tid >> 6;        // 0..7
    const int quad = lane >> 4;
    const int l15  = lane & 15;
    // XCD-clustered id decomposition: all 16 blocks of a group share blockIdx%8,
    // which the dispatcher maps round-robin to one XCD (verified at runtime below).
    const int xcd  = blockIdx.x & 7;
    const int slot = blockIdx.x >> 3;        // 0..31
    const int c    = slot & 15;              // col block / vocab slab
    const int g    = xcd + 8 * (slot >> 4);  // row group
    const int m0 = g * 16;
    const int n0 = c * 64;
    const int k0 = w * 128;           // K-slice for Wh / Wot GEMMs
    const int v0 = w * 32;            // K-slice for Xproj GEMM (V=256 / 8)
    int* gflg = flg + g * 16;

    // hoisted B fragments (reloads come from hot L2 — never invalidated)
    const bf16* Bp = Wht + (size_t)(n0 + l15) * N_SZ + k0 + quad * 8;
    bf16x8 b[4][4];
#pragma unroll
    for (int nt = 0; nt < 4; ++nt)
#pragma unroll
        for (int kc = 0; kc < 4; ++kc)
            b[nt][kc] = *(const bf16x8*)&Bp[(size_t)(nt * 16) * N_SZ + kc * 32];
    bf16x8 bx[4];
#pragma unroll
    for (int nt = 0; nt < 4; ++nt)
        bx[nt] = *(const bf16x8*)&Wxt[(size_t)(n0 + nt * 16 + l15) * V_SZ + v0 + quad * 8];
    bf16x8 bo[4];
#pragma unroll
    for (int kc = 0; kc < 4; ++kc)
        bo[kc] = *(const bf16x8*)&Wot[(size_t)(c * 16 + l15) * N_SZ + k0 + kc * 32 + quad * 8];

    // ---- runtime placement verification (one-time, permutation-agnostic) ----
    int myxcc;
    asm volatile("s_getreg_b32 %0, hwreg(HW_REG_XCC_ID)" : "=s"(myxcc));
    if (tid == 0)
        __hip_atomic_store(&xtab[g * 16 + c], myxcc & 15,
                           __ATOMIC_RELAXED, __HIP_MEMORY_SCOPE_AGENT);
    int fastv;
    {
        int v;
        while (true) {
            v = __hip_atomic_load(&xtab[g * 16 + (lane & 15)],
                                  __ATOMIC_RELAXED, __HIP_MEMORY_SCOPE_AGENT);
            if (__all(v != -1)) break;
            __builtin_amdgcn_s_sleep(8);
        }
        int ref = __shfl(v, 0, 64);
        fastv = __all(v == ref) ? 1 : 0;
    }

    const int orow = tid >> 5;           // 0..15
    const int ocol = (tid & 31) * 2;     // 0..62
    const float bias0 = bias[n0 + ocol];
    const float bias1 = bias[n0 + ocol + 1];
    // loss epilogue mapping: 16 lanes/wave, rows w*2+(lane>>3), vp = lane&7
    const int lrow = w * 2 + (lane >> 3);
    const int lvp  = lane & 7;
    unsigned int* XHu = (unsigned int*)XH;
    const f32x4 zz = {0.f, 0.f, 0.f, 0.f};
    const size_t xin = (size_t)(m0 + l15) * V_SZ + v0 + quad * 8;
    const int* fpp = gflg + (lane & 15);          // agent-scope poll address
    const unsigned int boff = (lane & 15) * 4;    // byte offset for sc0 poll

    // ---------------- t = 0: H_0 = tanh(Xproj_0 + bias) ----------------
    {
        float4 f0 = *(const float4*)&Xf[xin];
        float4 f1 = *(const float4*)&Xf[xin + 4];
        bf16x8 ax = cvt_bf16x8(f0, f1);
        f32x4 acc[4] = {zz, zz, zz, zz};
#pragma unroll
        for (int nt = 0; nt < 4; ++nt)
            acc[nt] = __builtin_amdgcn_mfma_f32_16x16x32_bf16(ax, bx[nt], acc[nt], 0, 0, 0);
#pragma unroll
        for (int nt = 0; nt < 4; ++nt)
#pragma unroll
            for (int r = 0; r < 4; ++r)
                red[(w * 16 + quad * 4 + r) * RSTR + nt * 16 + l15] = acc[nt][r];
        __syncthreads();
        float s0 = bias0, s1 = bias1;
#pragma unroll
        for (int w2 = 0; w2 < 8; ++w2) {
            float2 v = *(const float2*)&red[(w2 * 16 + orow) * RSTR + ocol];
            s0 += v.x; s1 += v.y;
        }
        bf16 r0 = (bf16)fast_tanh(s0);
        bf16 r1 = (bf16)fast_tanh(s1);
        unsigned int outw = (unsigned int)__builtin_bit_cast(unsigned short, r0)
                          | ((unsigned int)__builtin_bit_cast(unsigned short, r1) << 16);
        size_t oidx = (((size_t)m0 + orow) * N_SZ + n0 + ocol) >> 1;
        if (fastv)
            __hip_atomic_store(&XHu[oidx], outw, __ATOMIC_RELAXED, __HIP_MEMORY_SCOPE_WORKGROUP);
        else
            __hip_atomic_store(&XHu[oidx], outw, __ATOMIC_RELAXED, __HIP_MEMORY_SCOPE_AGENT);
        asm volatile("s_waitcnt vmcnt(0)" ::: "memory");
        __syncthreads();
        if (tid == 0) {
            if (fastv)
                __hip_atomic_store(&gflg[c], 1, __ATOMIC_RELAXED, __HIP_MEMORY_SCOPE_WORKGROUP);
            else
                __hip_atomic_store(&gflg[c], 1, __ATOMIC_RELAXED, __HIP_MEMORY_SCOPE_AGENT);
        }
    }

    // ---------------- t = 1 .. 127 ----------------
    for (int t = 1; t < T_STEPS; ++t) {
        // Xproj input prefetch + Xproj MFMAs BEFORE the poll (no H dependency)
        float4 f0 = *(const float4*)&Xf[(size_t)t * B_SZ * V_SZ + xin];
        float4 f1 = *(const float4*)&Xf[(size_t)t * B_SZ * V_SZ + xin + 4];
        bf16x8 ax = cvt_bf16x8(f0, f1);
        f32x4 acc[4] = {zz, zz, zz, zz};
#pragma unroll
        for (int nt = 0; nt < 4; ++nt)
            acc[nt] = __builtin_amdgcn_mfma_f32_16x16x32_bf16(ax, bx[nt], acc[nt], 0, 0, 0);
        asm volatile("" : "+v"(acc[0]), "+v"(acc[1]), "+v"(acc[2]), "+v"(acc[3]));

        // poll all 16 producer flags of plane t-1 (one 64B line); watchdogged
        {
            int fv = fastv, guard = 0;
            while (true) {
                int v;
                if (fv) {
                    asm volatile("global_load_dword %0, %1, %2 sc0\n\t"
                                 "s_waitcnt vmcnt(0)"
                                 : "=v"(v) : "v"(boff), "s"(gflg) : "memory");
                } else {
                    v = __hip_atomic_load(fpp, __ATOMIC_RELAXED, __HIP_MEMORY_SCOPE_AGENT);
                }
                if (__all(v >= t)) break;
                __builtin_amdgcn_s_sleep(1);
                if (fv && ++guard > SPIN_CAP) fv = 0;   // anti-hang escape hatch
            }
        }
        asm volatile("" ::: "memory");

        // A fragments: 16 rows of H_{t-1} (first-touch load => fresh L2/L3)
        const bf16* Ap = XH + ((size_t)(t - 1) * B_SZ + m0 + l15) * N_SZ + k0 + quad * 8;
        bf16x8 a[4];
#pragma unroll
        for (int kc = 0; kc < 4; ++kc)
            a[kc] = *(const bf16x8*)&Ap[kc * 32];

#pragma unroll
        for (int kc = 0; kc < 4; ++kc)
#pragma unroll
            for (int nt = 0; nt < 4; ++nt)
                acc[nt] = __builtin_amdgcn_mfma_f32_16x16x32_bf16(a[kc], b[nt][kc],
                                                                  acc[nt], 0, 0, 0);
        // loss MFMAs for plane t-1 (reuses a[])
        f32x4 lacc = zz;
#pragma unroll
        for (int kc = 0; kc < 4; ++kc)
            lacc = __builtin_amdgcn_mfma_f32_16x16x32_bf16(a[kc], bo[kc], lacc, 0, 0, 0);

        // both K-reduce writes in ONE window (lred parity-double-buffered)
#pragma unroll
        for (int nt = 0; nt < 4; ++nt)
#pragma unroll
            for (int r = 0; r < 4; ++r)
                red[(w * 16 + quad * 4 + r) * RSTR + nt * 16 + l15] = acc[nt][r];
#pragma unroll
        for (int r = 0; r < 4; ++r)
            lred[t & 1][(w * 16 + quad * 4 + r) * LSTR + l15] = lacc[r];
        __syncthreads();   // #2: red/lred writes -> reads

        // step epilogue: reduce, tanh, publish H_t
        float s0 = bias0, s1 = bias1;
#pragma unroll
        for (int w2 = 0; w2 < 8; ++w2) {
            float2 v = *(const float2*)&red[(w2 * 16 + orow) * RSTR + ocol];
            s0 += v.x; s1 += v.y;
        }
        bf16 r0 = (bf16)fast_tanh(s0);
        bf16 r1 = (bf16)fast_tanh(s1);
        unsigned int outw = (unsigned int)__builtin_bit_cast(unsigned short, r0)
                          | ((unsigned int)__builtin_bit_cast(unsigned short, r1) << 16);
        size_t oidx = (((size_t)t * B_SZ + m0 + orow) * N_SZ + n0 + ocol) >> 1;
        if (fastv)
            __hip_atomic_store(&XHu[oidx], outw, __ATOMIC_RELAXED, __HIP_MEMORY_SCOPE_WORKGROUP);
        else
            __hip_atomic_store(&XHu[oidx], outw, __ATOMIC_RELAXED, __HIP_MEMORY_SCOPE_AGENT);

        // drain H stores (deferred logit store of t-1 is long retired), barrier
        // (also closes red/lred read WAR), publish — the ONLY inter-block edge
        asm volatile("s_waitcnt vmcnt(0)" ::: "memory");
        __syncthreads();   // #B
        if (tid == 0) {
            if (fastv)
                __hip_atomic_store(&gflg[c], t + 1, __ATOMIC_RELAXED, __HIP_MEMORY_SCOPE_WORKGROUP);
            else
                __hip_atomic_store(&gflg[c], t + 1, __ATOMIC_RELAXED, __HIP_MEMORY_SCOPE_AGENT);
        }

        // ---- deferred loss epilogue for plane t-1 (off the publish edge) ----
        // WAR-safe: parity p=t&1 is next WRITTEN in iteration t+2; any wave's
        // write there is preceded by its passage through #2(t+1)/#B(t+1), which
        // requires THIS wave to have arrived there too — after these reads.
        if (lane < 16) {
            float sa = 0.f, sb = 0.f;
#pragma unroll
            for (int w2 = 0; w2 < 8; ++w2) {
                sa += lred[t & 1][(w2 * 16 + lrow) * LSTR + lvp * 2];
                sb += lred[t & 1][(w2 * 16 + lrow) * LSTR + lvp * 2 + 1];
            }
            bf16 pa = (bf16)sa, pb = (bf16)sb;
            unsigned int pw = (unsigned int)__builtin_bit_cast(unsigned short, pa)
                            | ((unsigned int)__builtin_bit_cast(unsigned short, pb) << 16);
            Lgu[(((size_t)(t - 1) * 16 + c) * B_SZ + m0 + lrow) * 8 + lvp] = pw;
        }
    }

    // ---------------- tail: loss GEMM for plane 127 ----------------
    {
        int fv = fastv, guard = 0;
        while (true) {
            int v;
            if (fv) {
                asm volatile("global_load_dword %0, %1, %2 sc0\n\t"
                             "s_waitcnt vmcnt(0)"
                             : "=v"(v) : "v"(boff), "s"(gflg) : "memory");
            } else {
                v = __hip_atomic_load(fpp, __ATOMIC_RELAXED, __HIP_MEMORY_SCOPE_AGENT);
            }
            if (__all(v >= T_STEPS)) break;
            __builtin_amdgcn_s_sleep(1);
            if (fv && ++guard > SPIN_CAP) fv = 0;
        }
        asm volatile("" ::: "memory");
        const bf16* Ap = XH + ((size_t)(T_STEPS - 1) * B_SZ + m0 + l15) * N_SZ + k0 + quad * 8;
        bf16x8 a[4];
#pragma unroll
        for (int kc = 0; kc < 4; ++kc)
            a[kc] = *(const bf16x8*)&Ap[kc * 32];
        f32x4 lacc = zz;
#pragma unroll
        for (int kc = 0; kc < 4; ++kc)
            lacc = __builtin_amdgcn_mfma_f32_16x16x32_bf16(a[kc], bo[kc], lacc, 0, 0, 0);
        // parity 0 free here: last parity-0 loop reads (t=126) were closed by the
        // collective #2(127)/#B(127); in-flight t=127 deferred reads use parity 1.
#pragma unroll
        for (int r = 0; r < 4; ++r)
            lred[0][(w * 16 + quad * 4 + r) * LSTR + l15] = lacc[r];
        __syncthreads();
        if (lane < 16) {
            float sa = 0.f, sb = 0.f;
#pragma unroll
            for (int w2 = 0; w2 < 8; ++w2) {
                sa += lred[0][(w2 * 16 + lrow) * LSTR + lvp * 2];
                sb += lred[0][(w2 * 16 + lrow) * LSTR + lvp * 2 + 1];
            }
            bf16 pa = (bf16)sa, pb = (bf16)sb;
            unsigned int pw = (unsigned int)__builtin_bit_cast(unsigned short, pa)
                            | ((unsigned int)__builtin_bit_cast(unsigned short, pb) << 16);
            Lgu[(((size_t)(T_STEPS - 1) * 16 + c) * B_SZ + m0 + lrow) * 8 + lvp] = pw;
        }
    }
}

// ---------------- final: log-softmax + weighted-label loss over bf16 logits --------
// 256 blocks x 256 threads (4 waves); block handles 128 rows, wave 32 rows.
// Logits layout: [plane][cslab 16][row-in-plane 256][16 vocab] bf16.
// (k_rnn's dirty L2 lines are flushed by the end-of-dispatch release, so plain
//  cross-kernel reads here are safe regardless of which XCD wrote them.)
__global__ __launch_bounds__(256) void k_lred(
    const bf16* __restrict__ Lg,
    const float* __restrict__ labels,
    const float* __restrict__ ob,
    float* __restrict__ out)
{
    __shared__ float bt[4];
    const int tid  = threadIdx.x;
    const int lane = tid & 63;
    const int w    = tid >> 6;       // 0..3
    const int cs   = lane >> 2;      // vocab slab 0..15
    const int vi   = (lane & 3) * 4; // offset in slab
    const float4 ob4 = *(const float4*)&ob[cs * 16 + vi];

    float wtot = 0.f;
    for (int i = 0; i < 32; ++i) {
        int row  = blockIdx.x * 128 + w * 32 + i;
        int p    = row >> 8;
        int brow = row & 255;
        bf16x4 lv = *(const bf16x4*)&Lg[(((size_t)p * 16 + cs) * B_SZ + brow) * 16 + vi];
        float l0 = (float)lv.x + ob4.x;
        float l1 = (float)lv.y + ob4.y;
        float l2 = (float)lv.z + ob4.z;
        float l3 = (float)lv.w + ob4.w;
        float mx = fmaxf(fmaxf(l0, l1), fmaxf(l2, l3));
#pragma unroll
        for (int sft = 1; sft < 64; sft <<= 1)
            mx = fmaxf(mx, __shfl_xor(mx, sft, 64));
        float sume = __expf(l0 - mx) + __expf(l1 - mx) + __expf(l2 - mx) + __expf(l3 - mx);
        const float4 lb = *(const float4*)&labels[(size_t)row * V_SZ + cs * 16 + vi];
        float labs = lb.x + lb.y + lb.z + lb.w;
        float labv = lb.x * l0 + lb.y * l1 + lb.z * l2 + lb.w * l3;
#pragma unroll
        for (int sft = 1; sft < 64; sft <<= 1) {
            sume += __shfl_xor(sume, sft, 64);
            labs += __shfl_xor(labs, sft, 64);
            labv += __shfl_xor(labv, sft, 64);
        }
        float lse = mx + __logf(sume);
        wtot += labs * lse - labv;
    }
    if (lane == 0) bt[w] = wtot;
    __syncthreads();
    if (tid == 0)
        atomicAdd(out, (bt[0] + bt[1] + bt[2] + bt[3]) * (1.0f / (float)NROWS));
}

extern "C" void kernel_launch(void* const* d_in, const int* in_sizes, int n_in,
                              void* d_out, int out_size, void* d_ws, size_t ws_size,
                              hipStream_t stream)
{
    const float* inputs  = (const float*)d_in[0];
    const float* labels  = (const float*)d_in[1];
    const float* weights = (const float*)d_in[2];
    const float* bias    = (const float*)d_in[3];
    const float* out_w   = (const float*)d_in[4];
    const float* out_b   = (const float*)d_in[5];
    float* out = (float*)d_out;

    char* ws = (char*)d_ws;
    bf16* XH   = (bf16*)ws;  ws += (size_t)NROWS * N_SZ * 2;   // 64 MB H states
    bf16* Lg   = (bf16*)ws;  ws += (size_t)NROWS * V_SZ * 2;   // 16 MB logits (slab)
    bf16* Wxt  = (bf16*)ws;  ws += (size_t)N_SZ * V_SZ * 2;    // 0.5 MB (Wx^T)
    bf16* Wht  = (bf16*)ws;  ws += (size_t)N_SZ * N_SZ * 2;    // 2 MB   (Wh^T)
    bf16* Wot  = (bf16*)ws;  ws += (size_t)V_SZ * N_SZ * 2;    // 0.5 MB (Wo^T)
    int*  flg  = (int*)ws;   ws += (size_t)(NGRP * 16 + 64) * 4; // flags (+pad)
    int*  xtab = (int*)ws;   ws += (size_t)NGRP * 16 * 4;        // XCC table

    hipMemsetAsync(out, 0, sizeof(float), stream);
    hipMemsetAsync(flg, 0, (size_t)(NGRP * 16 + 64) * 4, stream);
    hipMemsetAsync(xtab, 0xFF, (size_t)NGRP * 16 * 4, stream);

    k_prep<<<dim3(1536), 256, 0, stream>>>(weights, out_w, Wxt, Wht, Wot);

    k_rnn<<<dim3(NGRP * NCB), 512, 0, stream>>>(inputs, Wxt, Wht, Wot, bias, XH,
                                                (unsigned int*)Lg, flg, xtab);

    k_lred<<<dim3(NROWS / 128), 256, 0, stream>>>(Lg, labels, out_b, out);
}

// Round 6
// 473.359 us; speedup vs baseline: 1838.5824x; 1838.5824x over previous
//
#include <hip/hip_runtime.h>
#include <math.h>

typedef __bf16 bf16;
typedef __attribute__((ext_vector_type(4))) __bf16 bf16x4;
typedef __attribute__((ext_vector_type(8))) __bf16 bf16x8;
typedef __attribute__((ext_vector_type(4))) float f32x4;

#define T_STEPS 128
#define B_SZ    256
#define V_SZ    256
#define N_SZ    1024
#define NROWS   (T_STEPS * B_SZ)   // 32768
#define RSTR    68                 // step reduction stride (floats)
#define LSTR    17                 // loss reduction stride (floats)
#define NGRP    16                 // row groups (16 batch rows each)
#define NCB     16                 // col blocks per group (64 cols each)

__device__ __forceinline__ float fast_tanh(float x) {
    float e = __expf(2.0f * x);
    return 1.0f - 2.0f / (e + 1.0f);   // exact at +-inf, no NaN
}

__device__ __forceinline__ bf16x8 cvt_bf16x8(float4 a, float4 b) {
    bf16x8 r;
    r[0] = (bf16)a.x; r[1] = (bf16)a.y; r[2] = (bf16)a.z; r[3] = (bf16)a.w;
    r[4] = (bf16)b.x; r[5] = (bf16)b.y; r[6] = (bf16)b.z; r[7] = (bf16)b.w;
    return r;
}

// ---------------- one-shot prep: all three fp32->bf16 transposes -------------------
__global__ __launch_bounds__(256) void k_prep(
    const float* __restrict__ weights,   // (V+N) x N  = 1280 x 1024
    const float* __restrict__ out_w,     // N x V      = 1024 x 256
    bf16* __restrict__ Wxt,              // 1024 x 256
    bf16* __restrict__ Wht,              // 1024 x 1024
    bf16* __restrict__ Wot)              // 256 x 1024
{
    __shared__ float tile[32][33];
    int id = blockIdx.x;
    const float* src; bf16* dst; int R, C, tr, tc;
    if (id < 256) {            // Wx: rows 0..255 of weights -> Wxt
        src = weights; dst = Wxt; R = V_SZ; C = N_SZ;
        tr = (id & 7) * 32; tc = (id >> 3) * 32;
    } else if (id < 1280) {    // Wh: rows 256..1279 of weights -> Wht
        id -= 256;
        src = weights + (size_t)V_SZ * N_SZ; dst = Wht; R = N_SZ; C = N_SZ;
        tr = (id & 31) * 32; tc = (id >> 5) * 32;
    } else {                   // Wo: out_w -> Wot
        id -= 1280;
        src = out_w; dst = Wot; R = N_SZ; C = V_SZ;
        tr = (id & 31) * 32; tc = (id >> 5) * 32;
    }
    int tx = threadIdx.x & 31;
    int ty = threadIdx.x >> 5;   // 0..7
#pragma unroll
    for (int i = 0; i < 32; i += 8)
        tile[ty + i][tx] = src[(size_t)(tr + ty + i) * C + tc + tx];
    __syncthreads();
#pragma unroll
    for (int i = 0; i < 32; i += 8)
        dst[(size_t)(tc + ty + i) * R + tr + tx] = (bf16)tile[tx][ty + i];
}

// ---------------- persistent recurrence + fused Xproj + fused loss GEMM ------------
// R17 = EXACT R14 kernel (best proven: counter sync, 16 arrivals, K split across
// 8 waves, LDS K-reduce, in-loop loss GEMM) with its three proven latency cuts:
//   (1) counter load at loop top; Xproj cvt+MFMAs before the check (poll RTT hidden)
//   (2) per-wave uniform poll, no release barrier (WAR ordered by barrier #B)
//   (3) vmcnt(1) before #B (logit store, unread in-kernel, may stay in flight)
// R15/R16's XCD-L2 fast path is ABANDONED: empirically refuted (R16: 870 ms —
// workgroup-scope flags did not propagate between co-XCD blocks in bounded time).
__global__ __launch_bounds__(512, 2) void k_rnn(
    const float* __restrict__ Xf,   // 32768 x 256 fp32 inputs (t-major)
    const bf16* __restrict__ Wxt,   // 1024 x 256  = Wx^T
    const bf16* __restrict__ Wht,   // 1024 x 1024 = Wh^T
    const bf16* __restrict__ Wot,   // 256 x 1024  = Wo^T
    const float* __restrict__ bias,
    bf16* __restrict__ XH,          // 32768 x 1024 H states
    unsigned int* __restrict__ Lgu, // bf16-pair logits, slab layout [p][c][256][8]
    int* __restrict__ cnt)          // [NGRP * T_STEPS], zeroed
{
    __shared__ float red[8 * 16 * RSTR];   // 34.8 KB step K-reduce
    __shared__ float lred[8 * 16 * LSTR];  // 8.7 KB  loss K-reduce
    const int tid  = threadIdx.x;
    const int lane = tid & 63;
    const int w    = tid >> 6;        // 0..7
    const int quad = lane >> 4;
    const int l15  = lane & 15;
    const int g  = blockIdx.x >> 4;   // row group
    const int c  = blockIdx.x & 15;   // col block / vocab slab
    const int m0 = g * 16;
    const int n0 = c * 64;
    const int k0 = w * 128;           // K-slice for Wh / Wot GEMMs
    const int v0 = w * 32;            // K-slice for Xproj GEMM (V=256 / 8)
    int* gcnt = cnt + g * T_STEPS;

    // hoisted B fragments (reloads come from hot L2 — never invalidated)
    const bf16* Bp = Wht + (size_t)(n0 + l15) * N_SZ + k0 + quad * 8;
    bf16x8 b[4][4];
#pragma unroll
    for (int nt = 0; nt < 4; ++nt)
#pragma unroll
        for (int kc = 0; kc < 4; ++kc)
            b[nt][kc] = *(const bf16x8*)&Bp[(size_t)(nt * 16) * N_SZ + kc * 32];
    bf16x8 bx[4];
#pragma unroll
    for (int nt = 0; nt < 4; ++nt)
        bx[nt] = *(const bf16x8*)&Wxt[(size_t)(n0 + nt * 16 + l15) * V_SZ + v0 + quad * 8];
    bf16x8 bo[4];
#pragma unroll
    for (int kc = 0; kc < 4; ++kc)
        bo[kc] = *(const bf16x8*)&Wot[(size_t)(c * 16 + l15) * N_SZ + k0 + kc * 32 + quad * 8];

    const int orow = tid >> 5;           // 0..15
    const int ocol = (tid & 31) * 2;     // 0..62
    const float bias0 = bias[n0 + ocol];
    const float bias1 = bias[n0 + ocol + 1];
    // loss epilogue mapping: 16 lanes/wave, rows w*2+(lane>>3), vp = lane&7
    const int lrow = w * 2 + (lane >> 3);
    const int lvp  = lane & 7;
    unsigned int* XHu = (unsigned int*)XH;
    const f32x4 zz = {0.f, 0.f, 0.f, 0.f};
    const size_t xin = (size_t)(m0 + l15) * V_SZ + v0 + quad * 8;

    // ---------------- t = 0: H_0 = tanh(Xproj_0 + bias) ----------------
    {
        float4 f0 = *(const float4*)&Xf[xin];
        float4 f1 = *(const float4*)&Xf[xin + 4];
        bf16x8 ax = cvt_bf16x8(f0, f1);
        f32x4 acc[4] = {zz, zz, zz, zz};
#pragma unroll
        for (int nt = 0; nt < 4; ++nt)
            acc[nt] = __builtin_amdgcn_mfma_f32_16x16x32_bf16(ax, bx[nt], acc[nt], 0, 0, 0);
#pragma unroll
        for (int nt = 0; nt < 4; ++nt)
#pragma unroll
            for (int r = 0; r < 4; ++r)
                red[(w * 16 + quad * 4 + r) * RSTR + nt * 16 + l15] = acc[nt][r];
        __syncthreads();
        float s0 = bias0, s1 = bias1;
#pragma unroll
        for (int w2 = 0; w2 < 8; ++w2) {
            float2 v = *(const float2*)&red[(w2 * 16 + orow) * RSTR + ocol];
            s0 += v.x; s1 += v.y;
        }
        bf16 r0 = (bf16)fast_tanh(s0);
        bf16 r1 = (bf16)fast_tanh(s1);
        unsigned int outw = (unsigned int)__builtin_bit_cast(unsigned short, r0)
                          | ((unsigned int)__builtin_bit_cast(unsigned short, r1) << 16);
        size_t oidx = (((size_t)m0 + orow) * N_SZ + n0 + ocol) >> 1;
        __hip_atomic_store(&XHu[oidx], outw, __ATOMIC_RELAXED, __HIP_MEMORY_SCOPE_AGENT);
        asm volatile("s_waitcnt vmcnt(0)" ::: "memory");
        __syncthreads();
        if (tid == 0)
            __hip_atomic_fetch_add(&gcnt[0], 1, __ATOMIC_RELAXED, __HIP_MEMORY_SCOPE_AGENT);
    }

    // ---------------- t = 1 .. 127 ----------------
    for (int t = 1; t < T_STEPS; ++t) {
        // Xproj input prefetch (fp32) + EARLY counter read (in flight during Xproj)
        float4 f0 = *(const float4*)&Xf[(size_t)t * B_SZ * V_SZ + xin];
        float4 f1 = *(const float4*)&Xf[(size_t)t * B_SZ * V_SZ + xin + 4];
        int cv = __hip_atomic_load(&gcnt[t - 1], __ATOMIC_RELAXED,
                                   __HIP_MEMORY_SCOPE_AGENT);

        // Xproj MFMAs BEFORE the poll check — absorbs the detection RTT
        bf16x8 ax = cvt_bf16x8(f0, f1);
        f32x4 acc[4] = {zz, zz, zz, zz};
#pragma unroll
        for (int nt = 0; nt < 4; ++nt)
            acc[nt] = __builtin_amdgcn_mfma_f32_16x16x32_bf16(ax, bx[nt], acc[nt], 0, 0, 0);
        asm volatile("" : "+v"(acc[0]), "+v"(acc[1]), "+v"(acc[2]), "+v"(acc[3]));

        // per-wave uniform poll (all lanes, same line => 1 txn); no release barrier.
        // WAR on red/lred vs iteration t-1 is ordered by barrier #B below.
        while (cv < NCB) {
            __builtin_amdgcn_s_sleep(1);
            cv = __hip_atomic_load(&gcnt[t - 1], __ATOMIC_RELAXED,
                                   __HIP_MEMORY_SCOPE_AGENT);
        }
        asm volatile("" ::: "memory");

        // A fragments: 16 rows of H_{t-1} (first regular-load touch => fresh from L3)
        const bf16* Ap = XH + ((size_t)(t - 1) * B_SZ + m0 + l15) * N_SZ + k0 + quad * 8;
        bf16x8 a[4];
#pragma unroll
        for (int kc = 0; kc < 4; ++kc)
            a[kc] = *(const bf16x8*)&Ap[kc * 32];

#pragma unroll
        for (int kc = 0; kc < 4; ++kc)
#pragma unroll
            for (int nt = 0; nt < 4; ++nt)
                acc[nt] = __builtin_amdgcn_mfma_f32_16x16x32_bf16(a[kc], b[nt][kc],
                                                                  acc[nt], 0, 0, 0);
        // loss MFMAs for plane t-1 (reuses a[])
        f32x4 lacc = zz;
#pragma unroll
        for (int kc = 0; kc < 4; ++kc)
            lacc = __builtin_amdgcn_mfma_f32_16x16x32_bf16(a[kc], bo[kc], lacc, 0, 0, 0);

        // both K-reduce writes in ONE window
#pragma unroll
        for (int nt = 0; nt < 4; ++nt)
#pragma unroll
            for (int r = 0; r < 4; ++r)
                red[(w * 16 + quad * 4 + r) * RSTR + nt * 16 + l15] = acc[nt][r];
#pragma unroll
        for (int r = 0; r < 4; ++r)
            lred[(w * 16 + quad * 4 + r) * LSTR + l15] = lacc[r];
        __syncthreads();   // #2: red/lred writes -> reads

        // step epilogue: reduce, tanh, publish H_t (write-through dword)
        float s0 = bias0, s1 = bias1;
#pragma unroll
        for (int w2 = 0; w2 < 8; ++w2) {
            float2 v = *(const float2*)&red[(w2 * 16 + orow) * RSTR + ocol];
            s0 += v.x; s1 += v.y;
        }
        bf16 r0 = (bf16)fast_tanh(s0);
        bf16 r1 = (bf16)fast_tanh(s1);
        unsigned int outw = (unsigned int)__builtin_bit_cast(unsigned short, r0)
                          | ((unsigned int)__builtin_bit_cast(unsigned short, r1) << 16);
        size_t oidx = (((size_t)t * B_SZ + m0 + orow) * N_SZ + n0 + ocol) >> 1;
        __hip_atomic_store(&XHu[oidx], outw, __ATOMIC_RELAXED, __HIP_MEMORY_SCOPE_AGENT);
        // pin issue order: H-store (above) must precede the logit store below, so
        // vmcnt(1) provably covers the H-store (in-order vmcnt retirement).
        asm volatile("" ::: "memory");

        // loss epilogue (16 lanes per wave, own rows; slab layout = 1 line/wave)
        if (lane < 16) {
            float sa = 0.f, sb = 0.f;
#pragma unroll
            for (int w2 = 0; w2 < 8; ++w2) {
                sa += lred[(w2 * 16 + lrow) * LSTR + lvp * 2];
                sb += lred[(w2 * 16 + lrow) * LSTR + lvp * 2 + 1];
            }
            bf16 pa = (bf16)sa, pb = (bf16)sb;
            unsigned int pw = (unsigned int)__builtin_bit_cast(unsigned short, pa)
                            | ((unsigned int)__builtin_bit_cast(unsigned short, pb) << 16);
            Lgu[(((size_t)(t - 1) * 16 + c) * B_SZ + m0 + lrow) * 8 + lvp] = pw;
        }

        // drain all but the newest VMEM op (= the logit store): H-stores complete.
        asm volatile("s_waitcnt vmcnt(1)" ::: "memory");
        __syncthreads();   // #B: all waves' H-stores drained + LDS reads done
        if (tid == 0)
            __hip_atomic_fetch_add(&gcnt[t], 1, __ATOMIC_RELAXED, __HIP_MEMORY_SCOPE_AGENT);
    }

    // ---------------- tail: loss GEMM for plane 127 ----------------
    {
        int cv = __hip_atomic_load(&gcnt[T_STEPS - 1], __ATOMIC_RELAXED,
                                   __HIP_MEMORY_SCOPE_AGENT);
        while (cv < NCB) {
            __builtin_amdgcn_s_sleep(1);
            cv = __hip_atomic_load(&gcnt[T_STEPS - 1], __ATOMIC_RELAXED,
                                   __HIP_MEMORY_SCOPE_AGENT);
        }
        asm volatile("" ::: "memory");
        const bf16* Ap = XH + ((size_t)(T_STEPS - 1) * B_SZ + m0 + l15) * N_SZ + k0 + quad * 8;
        bf16x8 a[4];
#pragma unroll
        for (int kc = 0; kc < 4; ++kc)
            a[kc] = *(const bf16x8*)&Ap[kc * 32];
        f32x4 lacc = zz;
#pragma unroll
        for (int kc = 0; kc < 4; ++kc)
            lacc = __builtin_amdgcn_mfma_f32_16x16x32_bf16(a[kc], bo[kc], lacc, 0, 0, 0);
        // WAR vs iteration-127 lred reads: all waves passed #B(127) before exiting
        // the loop, so those reads are complete — tail writes are safe.
#pragma unroll
        for (int r = 0; r < 4; ++r)
            lred[(w * 16 + quad * 4 + r) * LSTR + l15] = lacc[r];
        __syncthreads();
        if (lane < 16) {
            float sa = 0.f, sb = 0.f;
#pragma unroll
            for (int w2 = 0; w2 < 8; ++w2) {
                sa += lred[(w2 * 16 + lrow) * LSTR + lvp * 2];
                sb += lred[(w2 * 16 + lrow) * LSTR + lvp * 2 + 1];
            }
            bf16 pa = (bf16)sa, pb = (bf16)sb;
            unsigned int pw = (unsigned int)__builtin_bit_cast(unsigned short, pa)
                            | ((unsigned int)__builtin_bit_cast(unsigned short, pb) << 16);
            Lgu[(((size_t)(T_STEPS - 1) * 16 + c) * B_SZ + m0 + lrow) * 8 + lvp] = pw;
        }
    }
}

// ---------------- final: log-softmax + weighted-label loss over bf16 logits --------
// R17: occupancy fix. Was 256 blocks x 256 thr (4 waves/CU, 12.5% occ) — the
// 24-deep shuffle chains per row were latency-exposed. Now 512 blocks x 512 thr
// (2 blocks/CU x 8 waves = 16 waves/CU): wave handles 8 rows, full unroll lets
// the compiler overlap row i+1 loads with row i's shuffle chain. Math unchanged.
// Logits layout: [plane][cslab 16][row-in-plane 256][16 vocab] bf16.
__global__ __launch_bounds__(512) void k_lred(
    const bf16* __restrict__ Lg,
    const float* __restrict__ labels,
    const float* __restrict__ ob,
    float* __restrict__ out)
{
    __shared__ float bt[8];
    const int tid  = threadIdx.x;
    const int lane = tid & 63;
    const int w    = tid >> 6;       // 0..7
    const int cs   = lane >> 2;      // vocab slab 0..15
    const int vi   = (lane & 3) * 4; // offset in slab
    const float4 ob4 = *(const float4*)&ob[cs * 16 + vi];

    float wtot = 0.f;
#pragma unroll
    for (int i = 0; i < 8; ++i) {
        int row  = blockIdx.x * 64 + w * 8 + i;
        int p    = row >> 8;
        int brow = row & 255;
        bf16x4 lv = *(const bf16x4*)&Lg[(((size_t)p * 16 + cs) * B_SZ + brow) * 16 + vi];
        float l0 = (float)lv.x + ob4.x;
        float l1 = (float)lv.y + ob4.y;
        float l2 = (float)lv.z + ob4.z;
        float l3 = (float)lv.w + ob4.w;
        float mx = fmaxf(fmaxf(l0, l1), fmaxf(l2, l3));
#pragma unroll
        for (int sft = 1; sft < 64; sft <<= 1)
            mx = fmaxf(mx, __shfl_xor(mx, sft, 64));
        float sume = __expf(l0 - mx) + __expf(l1 - mx) + __expf(l2 - mx) + __expf(l3 - mx);
        const float4 lb = *(const float4*)&labels[(size_t)row * V_SZ + cs * 16 + vi];
        float labs = lb.x + lb.y + lb.z + lb.w;
        float labv = lb.x * l0 + lb.y * l1 + lb.z * l2 + lb.w * l3;
#pragma unroll
        for (int sft = 1; sft < 64; sft <<= 1) {
            sume += __shfl_xor(sume, sft, 64);
            labs += __shfl_xor(labs, sft, 64);
            labv += __shfl_xor(labv, sft, 64);
        }
        float lse = mx + __logf(sume);
        wtot += labs * lse - labv;
    }
    if (lane == 0) bt[w] = wtot;
    __syncthreads();
    if (tid == 0) {
        float s = bt[0] + bt[1] + bt[2] + bt[3] + bt[4] + bt[5] + bt[6] + bt[7];
        atomicAdd(out, s * (1.0f / (float)NROWS));
    }
}

extern "C" void kernel_launch(void* const* d_in, const int* in_sizes, int n_in,
                              void* d_out, int out_size, void* d_ws, size_t ws_size,
                              hipStream_t stream)
{
    const float* inputs  = (const float*)d_in[0];
    const float* labels  = (const float*)d_in[1];
    const float* weights = (const float*)d_in[2];
    const float* bias    = (const float*)d_in[3];
    const float* out_w   = (const float*)d_in[4];
    const float* out_b   = (const float*)d_in[5];
    float* out = (float*)d_out;

    char* ws = (char*)d_ws;
    bf16* XH  = (bf16*)ws;  ws += (size_t)NROWS * N_SZ * 2;   // 64 MB H states
    bf16* Lg  = (bf16*)ws;  ws += (size_t)NROWS * V_SZ * 2;   // 16 MB logits (slab)
    bf16* Wxt = (bf16*)ws;  ws += (size_t)N_SZ * V_SZ * 2;    // 0.5 MB (Wx^T)
    bf16* Wht = (bf16*)ws;  ws += (size_t)N_SZ * N_SZ * 2;    // 2 MB   (Wh^T)
    bf16* Wot = (bf16*)ws;  ws += (size_t)V_SZ * N_SZ * 2;    // 0.5 MB (Wo^T)
    int*  cnt = (int*)ws;   ws += (size_t)NGRP * T_STEPS * 4; // 8 KB sync counters

    hipMemsetAsync(out, 0, sizeof(float), stream);
    hipMemsetAsync(cnt, 0, (size_t)NGRP * T_STEPS * 4, stream);

    k_prep<<<dim3(1536), 256, 0, stream>>>(weights, out_w, Wxt, Wht, Wot);

    k_rnn<<<dim3(NGRP * NCB), 512, 0, stream>>>(inputs, Wxt, Wht, Wot, bias, XH,
                                                (unsigned int*)Lg, cnt);

    k_lred<<<dim3(NROWS / 64), 512, 0, stream>>>(Lg, labels, out_b, out);
}